// Round 12
// baseline (1325.014 us; speedup 1.0000x reference)
//
#include <hip/hip_runtime.h>

#define NN 100000
#define NE 1600000
#define NG 512
#define DH 128
#define DH2 256
#define SCB 98      // ceil(NN / 1024)
#define NSTRIPE 32  // stats atomic striping

typedef __attribute__((ext_vector_type(8))) _Float16 h8;  // 8 f16 (4 VGPRs)
typedef __attribute__((ext_vector_type(2))) _Float16 h2;
typedef __attribute__((ext_vector_type(4))) float f4;     // MFMA C/D frag

static inline size_t align256(size_t x) { return (x + 255) & ~size_t(255); }

// ---- CSR build: slot trick (one atomic pass instead of two) -------------
__global__ __launch_bounds__(256) void countslot_k(const int* __restrict__ ei,
                                                   int* __restrict__ cursor,
                                                   int* __restrict__ slot) {
    int i = blockIdx.x * blockDim.x + threadIdx.x;
    int stride = gridDim.x * blockDim.x;
    for (int e = i; e < NE; e += stride)
        slot[e] = atomicAdd(&cursor[ei[NE + e]], 1);
}

__global__ __launch_bounds__(256) void place_k(const int* __restrict__ ei,
                                               const int* __restrict__ rowptr,
                                               const int* __restrict__ slot,
                                               int* __restrict__ esrc) {
    int i = blockIdx.x * blockDim.x + threadIdx.x;
    int stride = gridDim.x * blockDim.x;
    for (int e = i; e < NE; e += stride)
        esrc[rowptr[ei[NE + e]] + slot[e]] = ei[e];
}

__global__ void gbound_k(const int* __restrict__ batch, int* __restrict__ gcnt) {
    int g = blockIdx.x * blockDim.x + threadIdx.x;
    if (g >= NG) return;
    int lo = 0, hi = NN;
    while (lo < hi) { int m = (lo + hi) >> 1; if (batch[m] < g) lo = m + 1; else hi = m; }
    int b0 = lo;
    lo = 0; hi = NN;
    int g1 = g + 1;
    while (lo < hi) { int m = (lo + hi) >> 1; if (batch[m] < g1) lo = m + 1; else hi = m; }
    gcnt[g] = lo - b0;
}

// 3-kernel device-wide exclusive scan of deg[NN] -> rowptr
__global__ __launch_bounds__(256) void scan1_k(const int* __restrict__ deg,
                                               int* __restrict__ part) {
    int i0 = blockIdx.x * 1024 + threadIdx.x * 4;
    int s = 0;
    if (i0 < NN) {
        int4 v = *(const int4*)(deg + i0);
        s = v.x + v.y + v.z + v.w;
    }
#pragma unroll
    for (int o = 1; o < 64; o <<= 1) s += __shfl_xor(s, o);
    __shared__ int ws[4];
    if ((threadIdx.x & 63) == 0) ws[threadIdx.x >> 6] = s;
    __syncthreads();
    if (threadIdx.x == 0) part[blockIdx.x] = ws[0] + ws[1] + ws[2] + ws[3];
}

__global__ void scan2_k(int* __restrict__ part, int* __restrict__ rowptr) {
    if (threadIdx.x == 0) {
        int run = 0;
        for (int i = 0; i < SCB; i++) { int v = part[i]; part[i] = run; run += v; }
        rowptr[NN] = run;
    }
}

__global__ __launch_bounds__(256) void scan3_k(const int* __restrict__ deg,
                                               const int* __restrict__ part,
                                               int* __restrict__ rowptr) {
    int t = threadIdx.x;
    int i0 = blockIdx.x * 1024 + t * 4;
    int4 v = {0, 0, 0, 0};
    if (i0 < NN) v = *(const int4*)(deg + i0);
    int s = v.x + v.y + v.z + v.w;
    __shared__ int sc[256];
    sc[t] = s;
    __syncthreads();
    for (int o = 1; o < 256; o <<= 1) {
        int add = (t >= o) ? sc[t - o] : 0;
        __syncthreads();
        sc[t] += add;
        __syncthreads();
    }
    int excl = (t ? sc[t - 1] : 0) + part[blockIdx.x];
    if (i0 < NN) {
        int4 r;
        r.x = excl;
        r.y = excl + v.x;
        r.z = excl + v.x + v.y;
        r.w = excl + v.x + v.y + v.z;
        *(int4*)(rowptr + i0) = r;
    }
}

// ---- small ops ----------------------------------------------------------
__global__ void castx_k(const float* __restrict__ x, _Float16* __restrict__ xh) {
    int i = blockIdx.x * blockDim.x + threadIdx.x;  // NN*16 h8 chunks
    if (i >= NN * 16) return;
    const float4* s = (const float4*)x + i * 2;
    float4 p = s[0], q = s[1];
    h8 h = {(_Float16)p.x, (_Float16)p.y, (_Float16)p.z, (_Float16)p.w,
            (_Float16)q.x, (_Float16)q.y, (_Float16)q.z, (_Float16)q.w};
    ((h8*)xh)[i] = h;
}

__global__ void vinit_k(const float* __restrict__ emb, _Float16* __restrict__ vfeat) {
    int i = blockIdx.x * blockDim.x + threadIdx.x;  // NG*DH
    if (i < NG * DH) vfeat[i] = (_Float16)emb[i & (DH - 1)];
}

__global__ void zin_k(const float* __restrict__ pooled, const _Float16* __restrict__ vf,
                      _Float16* __restrict__ zb) {
    int i = blockIdx.x * blockDim.x + threadIdx.x;  // NG*DH
    if (i < NG * DH) zb[i] = (_Float16)(pooled[i] + (float)vf[i]);
}

__global__ void addvn_k(_Float16* __restrict__ x, const _Float16* __restrict__ vfeat,
                        const int* __restrict__ batch) {
    int i = blockIdx.x * blockDim.x + threadIdx.x;  // NN*16 h8 chunks
    if (i >= NN * 16) return;
    int row = i >> 4;
    int bg = batch[row];
    h8 u = ((h8*)x)[i];
    h8 v = ((const h8*)vfeat)[bg * 16 + (i & 15)];
    h8 o;
#pragma unroll
    for (int e = 0; e < 8; e++) o[e] = (_Float16)((float)u[e] + (float)v[e]);
    ((h8*)x)[i] = o;
}

__global__ void finalout_k(const float* __restrict__ pooled2, const int* __restrict__ gcnt,
                           float* __restrict__ outp) {
    int i = blockIdx.x * blockDim.x + threadIdx.x;
    if (i >= NG * DH) return;
    float cnt = (float)gcnt[i >> 7];
    outp[i] = pooled2[i] / fmaxf(cnt, 1.0f);
}

// ---- weight transpose+cast: W[K][N] f32 -> Wt[N][K] f16 -----------------
struct WPack {
    const float* w[8];
    _Float16* wt[8];
    int K[8];
    int N[8];
};
__global__ void wtrans_k(WPack p) {
    int id = blockIdx.z;
    const float* W = p.w[id];
    _Float16* Wt = p.wt[id];
    int K = p.K[id], N = p.N[id];
    int n0 = blockIdx.x * 32, k0 = blockIdx.y * 32;
    if (n0 >= N || k0 >= K) return;
    __shared__ float t[32][33];
    int tx = threadIdx.x & 31, ty = threadIdx.x >> 5;
    for (int i = 0; i < 32; i += 8)
        t[ty + i][tx] = W[(size_t)(k0 + ty + i) * N + n0 + tx];
    __syncthreads();
    for (int i = 0; i < 32; i += 8)
        Wt[(size_t)(n0 + ty + i) * K + k0 + tx] = (_Float16)t[tx][ty + i];
}

// ---- aggregation: out[n] = in[n] + sum_j in[src_j]  (f16 rows, f32 acc) -
__global__ __launch_bounds__(256) void agg_k(const _Float16* __restrict__ xin,
                                             const int* __restrict__ rowptr,
                                             const int* __restrict__ esrc,
                                             _Float16* __restrict__ out) {
    int wave = threadIdx.x >> 6, lane = threadIdx.x & 63;
    int node = blockIdx.x * 4 + wave;
    if (node >= NN) return;
    const h2* xr = (const h2*)xin;
    h2 self = xr[(size_t)node * 64 + lane];
    float a0 = (float)self.x, a1 = (float)self.y;
    int beg = rowptr[node], end = rowptr[node + 1];
    int j = beg;
    for (; j + 7 < end; j += 8) {
        int s0 = esrc[j],     s1 = esrc[j + 1], s2 = esrc[j + 2], s3 = esrc[j + 3];
        int s4 = esrc[j + 4], s5 = esrc[j + 5], s6 = esrc[j + 6], s7 = esrc[j + 7];
        h2 u0 = xr[(size_t)s0 * 64 + lane];
        h2 u1 = xr[(size_t)s1 * 64 + lane];
        h2 u2 = xr[(size_t)s2 * 64 + lane];
        h2 u3 = xr[(size_t)s3 * 64 + lane];
        h2 u4 = xr[(size_t)s4 * 64 + lane];
        h2 u5 = xr[(size_t)s5 * 64 + lane];
        h2 u6 = xr[(size_t)s6 * 64 + lane];
        h2 u7 = xr[(size_t)s7 * 64 + lane];
        a0 += ((float)u0.x + (float)u1.x) + ((float)u2.x + (float)u3.x)
            + ((float)u4.x + (float)u5.x) + ((float)u6.x + (float)u7.x);
        a1 += ((float)u0.y + (float)u1.y) + ((float)u2.y + (float)u3.y)
            + ((float)u4.y + (float)u5.y) + ((float)u6.y + (float)u7.y);
    }
    for (; j < end; j++) {
        h2 u = xr[(size_t)esrc[j] * 64 + lane];
        a0 += (float)u.x; a1 += (float)u.y;
    }
    h2 o; o.x = (_Float16)a0; o.y = (_Float16)a1;
    ((h2*)out)[(size_t)node * 64 + lane] = o;
}

// ---- last-block BN finalize (shared by both GEMMs) ----------------------
// Reduce the 32 stat stripes -> scale/shift once, inside the producing
// kernel's final block. Stripe reads use agent-scope atomic loads to avoid
// cross-XCD stale-L2 reads of atomically-updated lines.
__device__ __forceinline__ void bnfin_tail(
        float* __restrict__ csum, float* __restrict__ csq,
        const float* __restrict__ g, const float* __restrict__ b,
        float* __restrict__ scale, float* __restrict__ shift,
        int* __restrict__ done, int nblocks, int NC, int M, int tid) {
    __shared__ int lastflag;
    __threadfence();
    if (tid == 0) {
        int v = __hip_atomic_fetch_add(done, 1, __ATOMIC_ACQ_REL, __HIP_MEMORY_SCOPE_AGENT);
        lastflag = (v == nblocks - 1) ? 1 : 0;
    }
    __syncthreads();
    if (!lastflag) return;
    for (int col = tid; col < NC; col += 256) {
        float s = 0.f, q = 0.f;
        for (int st = 0; st < NSTRIPE; st++) {
            s += __hip_atomic_load(&csum[st * NC + col], __ATOMIC_RELAXED, __HIP_MEMORY_SCOPE_AGENT);
            q += __hip_atomic_load(&csq[st * NC + col], __ATOMIC_RELAXED, __HIP_MEMORY_SCOPE_AGENT);
        }
        float invM = 1.0f / (float)M;
        float mean = s * invM;
        float var = q * invM - mean * mean;
        float sc = g[col] * rsqrtf(var + 1e-5f);
        scale[col] = sc;
        shift[col] = b[col] - mean * sc;
    }
}

// ---- GEMM1: C[M x 256] = A[M x 128] @ W + bias (single A read) ----------
// acc 4x8 frags (both 128-col tiles per block); epilogue stages C in two
// halves through As; stats striped; BN finalize fused in last block.
__global__ __launch_bounds__(256, 2) void gemmA_k(
        const _Float16* __restrict__ A, const _Float16* __restrict__ Wt,
        const float* __restrict__ bias, _Float16* __restrict__ C,
        float* __restrict__ csum, float* __restrict__ csq, int M,
        const float* __restrict__ g, const float* __restrict__ b,
        float* __restrict__ scale, float* __restrict__ shift,
        int* __restrict__ done, int nblocks) {
    constexpr int K = 128, NCF = 256;
    constexpr int LDA = K + 8;
    __shared__ __align__(16) _Float16 As[128 * LDA];
    const int tid = threadIdx.x;
    const int lane = tid & 63;
    const int wave = tid >> 6;
    const int wr = wave & 1, wc = wave >> 1;
    const int lm = lane & 15, lq = lane >> 4;
    const int mB = blockIdx.x * 128;

    const int sr = tid >> 4;
    const int sc = (tid & 15) * 8;
#pragma unroll
    for (int rr = 0; rr < 128; rr += 16) {
        int gr = mB + rr + sr; if (gr >= M) gr = M - 1;
        *(h8*)&As[(rr + sr) * LDA + sc] = *(const h8*)&A[(size_t)gr * K + sc];
    }
    __syncthreads();

    f4 acc[4][8];
#pragma unroll
    for (int i = 0; i < 4; i++)
#pragma unroll
        for (int jj = 0; jj < 8; jj++) acc[i][jj] = (f4){0.f, 0.f, 0.f, 0.f};
#pragma unroll
    for (int ct = 0; ct < 2; ct++) {
        const int n0 = ct * 128 + wc * 64;
#pragma unroll
        for (int ks = 0; ks < 4; ks++) {
            h8 af[4], bf[4];
#pragma unroll
            for (int t = 0; t < 4; t++) {
                af[t] = *(const h8*)&As[(wr * 64 + t * 16 + lm) * LDA + ks * 32 + lq * 8];
                bf[t] = *(const h8*)&Wt[(size_t)(n0 + t * 16 + lm) * K + ks * 32 + lq * 8];
            }
#pragma unroll
            for (int i = 0; i < 4; i++)
#pragma unroll
                for (int j = 0; j < 4; j++)
                    acc[i][ct * 4 + j] =
                        __builtin_amdgcn_mfma_f32_16x16x32_f16(af[i], bf[j], acc[i][ct * 4 + j], 0, 0, 0);
        }
    }

    float bv[8];
#pragma unroll
    for (int jj = 0; jj < 8; jj++) bv[jj] = bias[(jj >> 2) * 128 + wc * 64 + (jj & 3) * 16 + lm];
    float ls[8] = {0, 0, 0, 0, 0, 0, 0, 0}, lsq[8] = {0, 0, 0, 0, 0, 0, 0, 0};
    _Float16* Cs = As;
    const int trow = tid >> 4;
    const int tcol = (tid & 15) * 8;
#pragma unroll
    for (int half = 0; half < 2; half++) {
        __syncthreads();
#pragma unroll
        for (int i = 0; i < 4; i++) {
            int row = wr * 64 + i * 16 + lq * 4;
#pragma unroll
            for (int j = 0; j < 4; j++) {
                int jj = half * 4 + j;
#pragma unroll
                for (int r = 0; r < 4; r++) {
                    float v = acc[i][jj][r] + bv[jj];
                    Cs[(row + r) * LDA + wc * 64 + j * 16 + lm] = (_Float16)v;
                    if (mB + row + r < M) { ls[jj] += v; lsq[jj] += v * v; }
                }
            }
        }
        __syncthreads();
#pragma unroll
        for (int p = 0; p < 8; p++) {
            int row = p * 16 + trow;
            int grow = mB + row;
            if (grow < M) {
                h8 v = *(const h8*)&Cs[row * LDA + tcol];
                *(h8*)&C[(size_t)grow * NCF + half * 128 + tcol] = v;
            }
        }
    }
    const int stripe = blockIdx.x & (NSTRIPE - 1);
#pragma unroll
    for (int jj = 0; jj < 8; jj++) {
        float s = ls[jj], q = lsq[jj];
        s += __shfl_xor(s, 16); s += __shfl_xor(s, 32);
        q += __shfl_xor(q, 16); q += __shfl_xor(q, 32);
        if (lq == 0) {
            int col = (jj >> 2) * 128 + wc * 64 + (jj & 3) * 16 + lm;
            atomicAdd(&csum[stripe * NCF + col], s);
            atomicAdd(&csq[stripe * NCF + col], q);
        }
    }
    bnfin_tail(csum, csq, g, b, scale, shift, done, nblocks, NCF, M, tid);
}

// ---- GEMM2: C[M x 128] = relu(bn(A)))[M x 256] @ W + bias ---------------
// BN+ReLU on A fused into staging via precomputed bnsc/bnsh[256];
// stats striped; BN finalize fused in last block.
__global__ __launch_bounds__(256, 2) void gemmB_k(
        const _Float16* __restrict__ A, const _Float16* __restrict__ Wt,
        const float* __restrict__ bias, _Float16* __restrict__ C,
        float* __restrict__ csum, float* __restrict__ csq, int M,
        const float* __restrict__ bnsc, const float* __restrict__ bnsh,
        const float* __restrict__ g, const float* __restrict__ b,
        float* __restrict__ scale, float* __restrict__ shift,
        int* __restrict__ done, int nblocks) {
    constexpr int K = 256, NCF = 128, BK = 128;
    constexpr int LDA = BK + 8;
    __shared__ __align__(16) _Float16 As[128 * LDA];
    const int tid = threadIdx.x;
    const int lane = tid & 63;
    const int wave = tid >> 6;
    const int wr = wave & 1, wc = wave >> 1;
    const int lm = lane & 15, lq = lane >> 4;
    const int mB = blockIdx.x * 128;
    const int n0 = wc * 64;

    f4 acc[4][4];
#pragma unroll
    for (int i = 0; i < 4; i++)
#pragma unroll
        for (int j = 0; j < 4; j++) acc[i][j] = (f4){0.f, 0.f, 0.f, 0.f};

    const int sr = tid >> 4;
    const int sc = (tid & 15) * 8;

    for (int kc = 0; kc < K; kc += BK) {
        if (kc) __syncthreads();
        float bscv[8], bshv[8];
        {
            float4 s0 = *(const float4*)&bnsc[kc + sc];
            float4 s1 = *(const float4*)&bnsc[kc + sc + 4];
            float4 t0 = *(const float4*)&bnsh[kc + sc];
            float4 t1 = *(const float4*)&bnsh[kc + sc + 4];
            bscv[0] = s0.x; bscv[1] = s0.y; bscv[2] = s0.z; bscv[3] = s0.w;
            bscv[4] = s1.x; bscv[5] = s1.y; bscv[6] = s1.z; bscv[7] = s1.w;
            bshv[0] = t0.x; bshv[1] = t0.y; bshv[2] = t0.z; bshv[3] = t0.w;
            bshv[4] = t1.x; bshv[5] = t1.y; bshv[6] = t1.z; bshv[7] = t1.w;
        }
#pragma unroll
        for (int rr = 0; rr < 128; rr += 16) {
            int gr = mB + rr + sr; if (gr >= M) gr = M - 1;
            h8 h = *(const h8*)&A[(size_t)gr * K + kc + sc];
#pragma unroll
            for (int e = 0; e < 8; e++)
                h[e] = (_Float16)fmaxf((float)h[e] * bscv[e] + bshv[e], 0.f);
            *(h8*)&As[(rr + sr) * LDA + sc] = h;
        }
        __syncthreads();
#pragma unroll
        for (int ks = 0; ks < BK / 32; ks++) {
            h8 af[4], bf[4];
#pragma unroll
            for (int t = 0; t < 4; t++) {
                af[t] = *(const h8*)&As[(wr * 64 + t * 16 + lm) * LDA + ks * 32 + lq * 8];
                bf[t] = *(const h8*)&Wt[(size_t)(n0 + t * 16 + lm) * K + kc + ks * 32 + lq * 8];
            }
#pragma unroll
            for (int i = 0; i < 4; i++)
#pragma unroll
                for (int j = 0; j < 4; j++)
                    acc[i][j] = __builtin_amdgcn_mfma_f32_16x16x32_f16(af[i], bf[j], acc[i][j], 0, 0, 0);
        }
    }

    float bv[4];
#pragma unroll
    for (int j = 0; j < 4; j++) bv[j] = bias[n0 + j * 16 + lm];
    float ls[4] = {0, 0, 0, 0}, lsq[4] = {0, 0, 0, 0};
    __syncthreads();
    _Float16* Cs = As;
#pragma unroll
    for (int i = 0; i < 4; i++) {
        int row = wr * 64 + i * 16 + lq * 4;
        bool rv[4];
#pragma unroll
        for (int r = 0; r < 4; r++) rv[r] = (mB + row + r) < M;
#pragma unroll
        for (int j = 0; j < 4; j++) {
#pragma unroll
            for (int r = 0; r < 4; r++) {
                float v = acc[i][j][r] + bv[j];
                Cs[(row + r) * LDA + wc * 64 + j * 16 + lm] = (_Float16)v;
                if (rv[r]) { ls[j] += v; lsq[j] += v * v; }
            }
        }
    }
    const int stripe = blockIdx.x & (NSTRIPE - 1);
#pragma unroll
    for (int j = 0; j < 4; j++) {
        float s = ls[j], q = lsq[j];
        s += __shfl_xor(s, 16); s += __shfl_xor(s, 32);
        q += __shfl_xor(q, 16); q += __shfl_xor(q, 32);
        if (lq == 0) {
            atomicAdd(&csum[stripe * NCF + n0 + j * 16 + lm], s);
            atomicAdd(&csq[stripe * NCF + n0 + j * 16 + lm], q);
        }
    }
    __syncthreads();
    const int trow = tid >> 4;
    const int tcol = (tid & 15) * 8;
#pragma unroll
    for (int p = 0; p < 8; p++) {
        int row = p * 16 + trow;
        int grow = mB + row;
        if (grow < M) {
            h8 v = *(const h8*)&Cs[row * LDA + tcol];
            *(h8*)&C[(size_t)grow * NCF + tcol] = v;
        }
    }
    bnfin_tail(csum, csq, g, b, scale, shift, done, nblocks, NCF, M, tid);
}

// ---- BN apply + relu (+optional vn-add after relu), f16 io, f32 math ----
__global__ void bnrelu_k(const _Float16* __restrict__ in, _Float16* __restrict__ out,
                         const float* __restrict__ scale, const float* __restrict__ shift,
                         const _Float16* __restrict__ vfeat, const int* __restrict__ batch,
                         int M) {
    constexpr int PER = 16;
    int tid = blockIdx.x * blockDim.x + threadIdx.x;
    int c8 = tid % PER;
    int c0 = c8 * 8;
    float sc[8], sh[8];
    float4 s0 = *(const float4*)&scale[c0];
    float4 s1 = *(const float4*)&scale[c0 + 4];
    float4 t0 = *(const float4*)&shift[c0];
    float4 t1 = *(const float4*)&shift[c0 + 4];
    sc[0] = s0.x; sc[1] = s0.y; sc[2] = s0.z; sc[3] = s0.w;
    sc[4] = s1.x; sc[5] = s1.y; sc[6] = s1.z; sc[7] = s1.w;
    sh[0] = t0.x; sh[1] = t0.y; sh[2] = t0.z; sh[3] = t0.w;
    sh[4] = t1.x; sh[5] = t1.y; sh[6] = t1.z; sh[7] = t1.w;
    int total = M * PER;
    int stride = gridDim.x * blockDim.x;
    for (int i = tid; i < total; i += stride) {
        int row = i / PER;
        h8 u = ((const h8*)in)[i];
        h8 w;
        bool vn = (vfeat != nullptr);
        if (vn) w = ((const h8*)vfeat)[batch[row] * PER + c8];
        h8 o;
#pragma unroll
        for (int e = 0; e < 8; e++) {
            float vv = fmaxf((float)u[e] * sc[e] + sh[e], 0.f);
            if (vn) vv += (float)w[e];
            o[e] = (_Float16)vv;
        }
        ((h8*)out)[i] = o;
    }
}

// ---- BN apply + segment-sum pool over sorted batch (NC=128) -------------
__global__ __launch_bounds__(256) void bnpool_k(
        const _Float16* __restrict__ in, _Float16* __restrict__ out,
        const float* __restrict__ scale, const float* __restrict__ shift,
        const int* __restrict__ batch, float* __restrict__ pooled,
        int M, int relu) {
    int t = threadIdx.x;
    int c0 = (t & 63) * 2;
    int r0 = blockIdx.x * 128 + (t >> 6) * 32;
    float sc0 = scale[c0], h0 = shift[c0];
    float sc1 = scale[c0 + 1], h1 = shift[c0 + 1];
    int rend = r0 + 32; if (rend > M) rend = M;
    float a0 = 0.f, a1 = 0.f; int cur = -1;
    int r = r0;
    for (; r + 1 < rend; r += 2) {
        h2 ua = ((const h2*)in)[(size_t)r * 64 + (c0 >> 1)];
        h2 ub = ((const h2*)in)[(size_t)(r + 1) * 64 + (c0 >> 1)];
        int bga = batch[r], bgb = batch[r + 1];
        float va0 = (float)ua.x * sc0 + h0, va1 = (float)ua.y * sc1 + h1;
        float vb0 = (float)ub.x * sc0 + h0, vb1 = (float)ub.y * sc1 + h1;
        if (relu) {
            va0 = fmaxf(va0, 0.f); va1 = fmaxf(va1, 0.f);
            vb0 = fmaxf(vb0, 0.f); vb1 = fmaxf(vb1, 0.f);
        }
        if (out) {
            h2 oa; oa.x = (_Float16)va0; oa.y = (_Float16)va1;
            h2 ob; ob.x = (_Float16)vb0; ob.y = (_Float16)vb1;
            ((h2*)out)[(size_t)r * 64 + (c0 >> 1)] = oa;
            ((h2*)out)[(size_t)(r + 1) * 64 + (c0 >> 1)] = ob;
        }
        if (bga != cur) {
            if (cur >= 0) {
                atomicAdd(&pooled[(size_t)cur * DH + c0], a0);
                atomicAdd(&pooled[(size_t)cur * DH + c0 + 1], a1);
            }
            cur = bga; a0 = 0.f; a1 = 0.f;
        }
        a0 += va0; a1 += va1;
        if (bgb != cur) {
            atomicAdd(&pooled[(size_t)cur * DH + c0], a0);
            atomicAdd(&pooled[(size_t)cur * DH + c0 + 1], a1);
            cur = bgb; a0 = 0.f; a1 = 0.f;
        }
        a0 += vb0; a1 += vb1;
    }
    for (; r < rend; r++) {
        h2 u = ((const h2*)in)[(size_t)r * 64 + (c0 >> 1)];
        float v0 = (float)u.x * sc0 + h0;
        float v1 = (float)u.y * sc1 + h1;
        if (relu) { v0 = fmaxf(v0, 0.f); v1 = fmaxf(v1, 0.f); }
        if (out) { h2 o; o.x = (_Float16)v0; o.y = (_Float16)v1; ((h2*)out)[(size_t)r * 64 + (c0 >> 1)] = o; }
        int bg = batch[r];
        if (bg != cur) {
            if (cur >= 0) {
                atomicAdd(&pooled[(size_t)cur * DH + c0], a0);
                atomicAdd(&pooled[(size_t)cur * DH + c0 + 1], a1);
            }
            cur = bg; a0 = 0.f; a1 = 0.f;
        }
        a0 += v0; a1 += v1;
    }
    if (cur >= 0) {
        atomicAdd(&pooled[(size_t)cur * DH + c0], a0);
        atomicAdd(&pooled[(size_t)cur * DH + c0 + 1], a1);
    }
}

// ------------------------------------------------------------------------
extern "C" void kernel_launch(void* const* d_in, const int* in_sizes, int n_in,
                              void* d_out, int out_size, void* d_ws, size_t ws_size,
                              hipStream_t stream) {
    const float* x      = (const float*)d_in[0];
    const int*   ei     = (const int*)d_in[1];
    const int*   batch  = (const int*)d_in[2];
    const float* vn_emb = (const float*)d_in[3];
    const float* c1_W1  = (const float*)d_in[4];
    const float* c1_b1  = (const float*)d_in[5];
    const float* c1_bng = (const float*)d_in[6];
    const float* c1_bnb = (const float*)d_in[7];
    const float* c1_W2  = (const float*)d_in[8];
    const float* c1_b2  = (const float*)d_in[9];
    const float* bn1_g  = (const float*)d_in[10];
    const float* bn1_b  = (const float*)d_in[11];
    const float* cW1    = (const float*)d_in[12];
    const float* cb1    = (const float*)d_in[13];
    const float* cbng   = (const float*)d_in[14];
    const float* cbnb   = (const float*)d_in[15];
    const float* cW2    = (const float*)d_in[16];
    const float* cb2    = (const float*)d_in[17];
    const float* bns_g  = (const float*)d_in[18];
    const float* bns_b  = (const float*)d_in[19];
    const float* vW1    = (const float*)d_in[20];
    const float* vb1    = (const float*)d_in[21];
    const float* vbn1_g = (const float*)d_in[22];
    const float* vbn1_b = (const float*)d_in[23];
    const float* vW2    = (const float*)d_in[24];
    const float* vb2    = (const float*)d_in[25];
    const float* vbn2_g = (const float*)d_in[26];
    const float* vbn2_b = (const float*)d_in[27];
    float* outp = (float*)d_out;
    (void)in_sizes; (void)n_in; (void)out_size; (void)ws_size;

    char* w = (char*)d_ws;
    size_t off = 0;
    auto carve = [&](size_t bytes) -> void* {
        void* p = w + off; off = align256(off + bytes); return p;
    };
    // zero-init region
    int*   cursor  = (int*)carve((size_t)NN * 4);
    float* pooled  = (float*)carve((size_t)NG * DH * 4);
    float* pooled2 = (float*)carve((size_t)NG * DH * 4);
    int*   done    = (int*)carve(8 * 4);
    float *sA[3], *qA[3], *sB[3], *qB[3], *sV1, *qV1, *sV2, *qV2;
    for (int i = 0; i < 3; i++) {
        sA[i] = (float*)carve((size_t)NSTRIPE * 256 * 4);
        qA[i] = (float*)carve((size_t)NSTRIPE * 256 * 4);
    }
    for (int i = 0; i < 3; i++) {
        sB[i] = (float*)carve((size_t)NSTRIPE * 128 * 4);
        qB[i] = (float*)carve((size_t)NSTRIPE * 128 * 4);
    }
    sV1 = (float*)carve((size_t)NSTRIPE * 256 * 4);
    qV1 = (float*)carve((size_t)NSTRIPE * 256 * 4);
    sV2 = (float*)carve((size_t)NSTRIPE * 128 * 4);
    qV2 = (float*)carve((size_t)NSTRIPE * 128 * 4);
    size_t zbytes = off;
    // non-zeroed region
    float *scA[3], *shA[3], *scB[3], *shB[3];
    for (int i = 0; i < 3; i++) { scA[i] = (float*)carve(256 * 4); shA[i] = (float*)carve(256 * 4); }
    for (int i = 0; i < 3; i++) { scB[i] = (float*)carve(128 * 4); shB[i] = (float*)carve(128 * 4); }
    float* scV1 = (float*)carve(256 * 4); float* shV1 = (float*)carve(256 * 4);
    float* scV2 = (float*)carve(128 * 4); float* shV2 = (float*)carve(128 * 4);
    int*   gcnt    = (int*)carve((size_t)NG * 4);
    int*   rowptr  = (int*)carve((size_t)(NN + 1) * 4);
    int*   slot    = (int*)carve((size_t)NE * 4);
    int*   esrc    = (int*)carve((size_t)NE * 4);
    int*   part    = (int*)carve((size_t)SCB * 4);
    _Float16* vfeat = (_Float16*)carve((size_t)NG * DH * 2);
    _Float16* zin   = (_Float16*)carve((size_t)NG * DH * 2);
    _Float16* zb    = (_Float16*)carve((size_t)NG * DH2 * 2);
    _Float16* vraw  = (_Float16*)carve((size_t)NG * DH * 2);
    _Float16* xh    = (_Float16*)carve((size_t)NN * DH * 2);
    _Float16* hb    = (_Float16*)carve((size_t)NN * DH * 2);
    _Float16* b1    = (_Float16*)carve((size_t)NN * DH2 * 2);
    _Float16* abuf  = (_Float16*)carve((size_t)NN * DH * 2);
    _Float16* Wt[8];
    for (int i = 0; i < 8; i++) Wt[i] = (_Float16*)carve((size_t)DH * DH2 * 2);

    WPack wp;
    wp.w[0] = c1_W1;            wp.K[0] = 128; wp.N[0] = 256;
    wp.w[1] = c1_W2;            wp.K[1] = 256; wp.N[1] = 128;
    wp.w[2] = cW1;              wp.K[2] = 128; wp.N[2] = 256;
    wp.w[3] = cW2;              wp.K[3] = 256; wp.N[3] = 128;
    wp.w[4] = cW1 + 128 * 256;  wp.K[4] = 128; wp.N[4] = 256;
    wp.w[5] = cW2 + 256 * 128;  wp.K[5] = 256; wp.N[5] = 128;
    wp.w[6] = vW1;              wp.K[6] = 128; wp.N[6] = 256;
    wp.w[7] = vW2;              wp.K[7] = 256; wp.N[7] = 128;
    for (int i = 0; i < 8; i++) wp.wt[i] = Wt[i];

    const int GB = (NN + 127) / 128;  // 782

    hipMemsetAsync(d_ws, 0, zbytes, stream);
    countslot_k<<<782, 256, 0, stream>>>(ei, cursor, slot);
    scan1_k<<<SCB, 256, 0, stream>>>(cursor, part);
    scan2_k<<<1, 64, 0, stream>>>(part, rowptr);
    scan3_k<<<SCB, 256, 0, stream>>>(cursor, part, rowptr);
    place_k<<<782, 256, 0, stream>>>(ei, rowptr, slot, esrc);
    gbound_k<<<2, 256, 0, stream>>>(batch, gcnt);
    wtrans_k<<<dim3(8, 8, 8), 256, 0, stream>>>(wp);
    vinit_k<<<(NG * DH + 255) / 256, 256, 0, stream>>>(vn_emb, vfeat);
    castx_k<<<(NN * 16 + 255) / 256, 256, 0, stream>>>(x, xh);

    // ---- layer 1 ----
    agg_k<<<NN / 4, 256, 0, stream>>>(xh, rowptr, esrc, hb);
    gemmA_k<<<GB, 256, 0, stream>>>(hb, Wt[0], c1_b1, b1, sA[0], qA[0], NN,
                                    c1_bng, c1_bnb, scA[0], shA[0], &done[0], GB);
    gemmB_k<<<GB, 256, 0, stream>>>(b1, Wt[1], c1_b2, abuf, sB[0], qB[0], NN,
                                    scA[0], shA[0], bn1_g, bn1_b, scB[0], shB[0], &done[1], GB);
    bnrelu_k<<<2048, 256, 0, stream>>>(abuf, abuf, scB[0], shB[0], vfeat, batch, NN);

    // ---- layer 2 ----
    agg_k<<<NN / 4, 256, 0, stream>>>(abuf, rowptr, esrc, hb);
    gemmA_k<<<GB, 256, 0, stream>>>(hb, Wt[2], cb1, b1, sA[1], qA[1], NN,
                                    cbng, cbnb, scA[1], shA[1], &done[2], GB);
    gemmB_k<<<GB, 256, 0, stream>>>(b1, Wt[3], cb2, abuf, sB[1], qB[1], NN,
                                    scA[1], shA[1], bns_g, bns_b, scB[1], shB[1], &done[3], GB);
    bnpool_k<<<GB, 256, 0, stream>>>(abuf, abuf, scB[1], shB[1], batch, pooled, NN, 1);

    // ---- virtual-node MLP (M = 512) ----
    zin_k<<<(NG * DH + 255) / 256, 256, 0, stream>>>(pooled, vfeat, zin);
    gemmA_k<<<4, 256, 0, stream>>>(zin, Wt[6], vb1, zb, sV1, qV1, NG,
                                   vbn1_g, vbn1_b, scV1, shV1, &done[6], 4);
    gemmB_k<<<4, 256, 0, stream>>>(zb, Wt[7], vb2, vraw, sV2, qV2, NG,
                                   scV1, shV1, vbn2_g, vbn2_b, scV2, shV2, &done[7], 4);
    bnrelu_k<<<32, 256, 0, stream>>>(vraw, vfeat, scV2, shV2, nullptr, nullptr, NG);

    // ---- layer 3 ----
    addvn_k<<<(NN * 16 + 255) / 256, 256, 0, stream>>>(abuf, vfeat, batch);
    agg_k<<<NN / 4, 256, 0, stream>>>(abuf, rowptr, esrc, hb);
    gemmA_k<<<GB, 256, 0, stream>>>(hb, Wt[4], cb1 + 256, b1, sA[2], qA[2], NN,
                                    cbng + 256, cbnb + 256, scA[2], shA[2], &done[4], GB);
    gemmB_k<<<GB, 256, 0, stream>>>(b1, Wt[5], cb2 + 128, abuf, sB[2], qB[2], NN,
                                    scA[2], shA[2], bns_g + 128, bns_b + 128, scB[2], shB[2],
                                    &done[5], GB);
    bnpool_k<<<GB, 256, 0, stream>>>(abuf, nullptr, scB[2], shB[2], batch, pooled2, NN, 0);

    finalout_k<<<(NG * DH + 255) / 256, 256, 0, stream>>>(pooled2, gcnt, outp);
}

// Round 13
// 810.016 us; speedup vs baseline: 1.6358x; 1.6358x over previous
//
#include <hip/hip_runtime.h>

#define NN 100000
#define NE 1600000
#define NG 512
#define DH 128
#define DH2 256
#define SCB 98      // ceil(NN / 1024)
#define NSTRIPE 32  // stats atomic striping

typedef __attribute__((ext_vector_type(8))) _Float16 h8;  // 8 f16 (4 VGPRs)
typedef __attribute__((ext_vector_type(2))) _Float16 h2;
typedef __attribute__((ext_vector_type(4))) float f4;     // MFMA C/D frag

static inline size_t align256(size_t x) { return (x + 255) & ~size_t(255); }

// ---- CSR build: slot trick (one atomic pass instead of two) -------------
__global__ __launch_bounds__(256) void countslot_k(const int* __restrict__ ei,
                                                   int* __restrict__ cursor,
                                                   int* __restrict__ slot) {
    int i = blockIdx.x * blockDim.x + threadIdx.x;
    int stride = gridDim.x * blockDim.x;
    for (int e = i; e < NE; e += stride)
        slot[e] = atomicAdd(&cursor[ei[NE + e]], 1);
}

__global__ __launch_bounds__(256) void place_k(const int* __restrict__ ei,
                                               const int* __restrict__ rowptr,
                                               const int* __restrict__ slot,
                                               int* __restrict__ esrc) {
    int i = blockIdx.x * blockDim.x + threadIdx.x;
    int stride = gridDim.x * blockDim.x;
    for (int e = i; e < NE; e += stride)
        esrc[rowptr[ei[NE + e]] + slot[e]] = ei[e];
}

__global__ void gbound_k(const int* __restrict__ batch, int* __restrict__ gcnt) {
    int g = blockIdx.x * blockDim.x + threadIdx.x;
    if (g >= NG) return;
    int lo = 0, hi = NN;
    while (lo < hi) { int m = (lo + hi) >> 1; if (batch[m] < g) lo = m + 1; else hi = m; }
    int b0 = lo;
    lo = 0; hi = NN;
    int g1 = g + 1;
    while (lo < hi) { int m = (lo + hi) >> 1; if (batch[m] < g1) lo = m + 1; else hi = m; }
    gcnt[g] = lo - b0;
}

// 3-kernel device-wide exclusive scan of deg[NN] -> rowptr
__global__ __launch_bounds__(256) void scan1_k(const int* __restrict__ deg,
                                               int* __restrict__ part) {
    int i0 = blockIdx.x * 1024 + threadIdx.x * 4;
    int s = 0;
    if (i0 < NN) {
        int4 v = *(const int4*)(deg + i0);
        s = v.x + v.y + v.z + v.w;
    }
#pragma unroll
    for (int o = 1; o < 64; o <<= 1) s += __shfl_xor(s, o);
    __shared__ int ws[4];
    if ((threadIdx.x & 63) == 0) ws[threadIdx.x >> 6] = s;
    __syncthreads();
    if (threadIdx.x == 0) part[blockIdx.x] = ws[0] + ws[1] + ws[2] + ws[3];
}

__global__ void scan2_k(int* __restrict__ part, int* __restrict__ rowptr) {
    if (threadIdx.x == 0) {
        int run = 0;
        for (int i = 0; i < SCB; i++) { int v = part[i]; part[i] = run; run += v; }
        rowptr[NN] = run;
    }
}

__global__ __launch_bounds__(256) void scan3_k(const int* __restrict__ deg,
                                               const int* __restrict__ part,
                                               int* __restrict__ rowptr) {
    int t = threadIdx.x;
    int i0 = blockIdx.x * 1024 + t * 4;
    int4 v = {0, 0, 0, 0};
    if (i0 < NN) v = *(const int4*)(deg + i0);
    int s = v.x + v.y + v.z + v.w;
    __shared__ int sc[256];
    sc[t] = s;
    __syncthreads();
    for (int o = 1; o < 256; o <<= 1) {
        int add = (t >= o) ? sc[t - o] : 0;
        __syncthreads();
        sc[t] += add;
        __syncthreads();
    }
    int excl = (t ? sc[t - 1] : 0) + part[blockIdx.x];
    if (i0 < NN) {
        int4 r;
        r.x = excl;
        r.y = excl + v.x;
        r.z = excl + v.x + v.y;
        r.w = excl + v.x + v.y + v.z;
        *(int4*)(rowptr + i0) = r;
    }
}

// ---- small ops ----------------------------------------------------------
__global__ void castx_k(const float* __restrict__ x, _Float16* __restrict__ xh) {
    int i = blockIdx.x * blockDim.x + threadIdx.x;  // NN*16 h8 chunks
    if (i >= NN * 16) return;
    const float4* s = (const float4*)x + i * 2;
    float4 p = s[0], q = s[1];
    h8 h = {(_Float16)p.x, (_Float16)p.y, (_Float16)p.z, (_Float16)p.w,
            (_Float16)q.x, (_Float16)q.y, (_Float16)q.z, (_Float16)q.w};
    ((h8*)xh)[i] = h;
}

__global__ void vinit_k(const float* __restrict__ emb, _Float16* __restrict__ vfeat) {
    int i = blockIdx.x * blockDim.x + threadIdx.x;  // NG*DH
    if (i < NG * DH) vfeat[i] = (_Float16)emb[i & (DH - 1)];
}

__global__ void zin_k(const float* __restrict__ pooled, const _Float16* __restrict__ vf,
                      _Float16* __restrict__ zb) {
    int i = blockIdx.x * blockDim.x + threadIdx.x;  // NG*DH
    if (i < NG * DH) zb[i] = (_Float16)(pooled[i] + (float)vf[i]);
}

__global__ void addvn_k(_Float16* __restrict__ x, const _Float16* __restrict__ vfeat,
                        const int* __restrict__ batch) {
    int i = blockIdx.x * blockDim.x + threadIdx.x;  // NN*16 h8 chunks
    if (i >= NN * 16) return;
    int row = i >> 4;
    int bg = batch[row];
    h8 u = ((h8*)x)[i];
    h8 v = ((const h8*)vfeat)[bg * 16 + (i & 15)];
    h8 o;
#pragma unroll
    for (int e = 0; e < 8; e++) o[e] = (_Float16)((float)u[e] + (float)v[e]);
    ((h8*)x)[i] = o;
}

__global__ void finalout_k(const float* __restrict__ pooled2, const int* __restrict__ gcnt,
                           float* __restrict__ outp) {
    int i = blockIdx.x * blockDim.x + threadIdx.x;
    if (i >= NG * DH) return;
    float cnt = (float)gcnt[i >> 7];
    outp[i] = pooled2[i] / fmaxf(cnt, 1.0f);
}

// ---- BN finalize: reduce stripes once -> scale/shift (read-only after) --
__global__ void bnfin_k(const float* __restrict__ csum, const float* __restrict__ csq,
                        const float* __restrict__ g, const float* __restrict__ b,
                        float* __restrict__ scale, float* __restrict__ shift,
                        int NC, int M) {
    int col = threadIdx.x;
    if (col >= NC) return;
    float s = 0.f, q = 0.f;
    for (int st = 0; st < NSTRIPE; st++) { s += csum[st * NC + col]; q += csq[st * NC + col]; }
    float invM = 1.0f / (float)M;
    float mean = s * invM;
    float var = q * invM - mean * mean;
    float sc = g[col] * rsqrtf(var + 1e-5f);
    scale[col] = sc;
    shift[col] = b[col] - mean * sc;
}

// ---- weight transpose+cast: W[K][N] f32 -> Wt[N][K] f16 -----------------
struct WPack {
    const float* w[8];
    _Float16* wt[8];
    int K[8];
    int N[8];
};
__global__ void wtrans_k(WPack p) {
    int id = blockIdx.z;
    const float* W = p.w[id];
    _Float16* Wt = p.wt[id];
    int K = p.K[id], N = p.N[id];
    int n0 = blockIdx.x * 32, k0 = blockIdx.y * 32;
    if (n0 >= N || k0 >= K) return;
    __shared__ float t[32][33];
    int tx = threadIdx.x & 31, ty = threadIdx.x >> 5;
    for (int i = 0; i < 32; i += 8)
        t[ty + i][tx] = W[(size_t)(k0 + ty + i) * N + n0 + tx];
    __syncthreads();
    for (int i = 0; i < 32; i += 8)
        Wt[(size_t)(n0 + ty + i) * K + k0 + tx] = (_Float16)t[tx][ty + i];
}

// ---- aggregation: out[n] = in[n] + sum_j in[src_j]  (f16 rows, f32 acc) -
__global__ __launch_bounds__(256) void agg_k(const _Float16* __restrict__ xin,
                                             const int* __restrict__ rowptr,
                                             const int* __restrict__ esrc,
                                             _Float16* __restrict__ out) {
    int wave = threadIdx.x >> 6, lane = threadIdx.x & 63;
    int node = blockIdx.x * 4 + wave;
    if (node >= NN) return;
    const h2* xr = (const h2*)xin;
    h2 self = xr[(size_t)node * 64 + lane];
    float a0 = (float)self.x, a1 = (float)self.y;
    int beg = rowptr[node], end = rowptr[node + 1];
    int j = beg;
    for (; j + 7 < end; j += 8) {
        int s0 = esrc[j],     s1 = esrc[j + 1], s2 = esrc[j + 2], s3 = esrc[j + 3];
        int s4 = esrc[j + 4], s5 = esrc[j + 5], s6 = esrc[j + 6], s7 = esrc[j + 7];
        h2 u0 = xr[(size_t)s0 * 64 + lane];
        h2 u1 = xr[(size_t)s1 * 64 + lane];
        h2 u2 = xr[(size_t)s2 * 64 + lane];
        h2 u3 = xr[(size_t)s3 * 64 + lane];
        h2 u4 = xr[(size_t)s4 * 64 + lane];
        h2 u5 = xr[(size_t)s5 * 64 + lane];
        h2 u6 = xr[(size_t)s6 * 64 + lane];
        h2 u7 = xr[(size_t)s7 * 64 + lane];
        a0 += ((float)u0.x + (float)u1.x) + ((float)u2.x + (float)u3.x)
            + ((float)u4.x + (float)u5.x) + ((float)u6.x + (float)u7.x);
        a1 += ((float)u0.y + (float)u1.y) + ((float)u2.y + (float)u3.y)
            + ((float)u4.y + (float)u5.y) + ((float)u6.y + (float)u7.y);
    }
    for (; j < end; j++) {
        h2 u = xr[(size_t)esrc[j] * 64 + lane];
        a0 += (float)u.x; a1 += (float)u.y;
    }
    h2 o; o.x = (_Float16)a0; o.y = (_Float16)a1;
    ((h2*)out)[(size_t)node * 64 + lane] = o;
}

// ---- GEMM1: C[M x 256] = A[M x 128] @ W + bias (single A read) ----------
// acc 4x8 frags (both 128-col tiles per block); epilogue stages C in two
// halves through As for coalesced 16B stores; stats striped (NO fused
// finalize — __threadfence per block was a 100µs/kernel disaster in R12).
__global__ __launch_bounds__(256, 2) void gemmA_k(
        const _Float16* __restrict__ A, const _Float16* __restrict__ Wt,
        const float* __restrict__ bias, _Float16* __restrict__ C,
        float* __restrict__ csum, float* __restrict__ csq, int M) {
    constexpr int K = 128, NCF = 256;
    constexpr int LDA = K + 8;
    __shared__ __align__(16) _Float16 As[128 * LDA];
    const int tid = threadIdx.x;
    const int lane = tid & 63;
    const int wave = tid >> 6;
    const int wr = wave & 1, wc = wave >> 1;
    const int lm = lane & 15, lq = lane >> 4;
    const int mB = blockIdx.x * 128;

    const int sr = tid >> 4;
    const int sc = (tid & 15) * 8;
#pragma unroll
    for (int rr = 0; rr < 128; rr += 16) {
        int gr = mB + rr + sr; if (gr >= M) gr = M - 1;
        *(h8*)&As[(rr + sr) * LDA + sc] = *(const h8*)&A[(size_t)gr * K + sc];
    }
    __syncthreads();

    f4 acc[4][8];
#pragma unroll
    for (int i = 0; i < 4; i++)
#pragma unroll
        for (int jj = 0; jj < 8; jj++) acc[i][jj] = (f4){0.f, 0.f, 0.f, 0.f};
#pragma unroll
    for (int ct = 0; ct < 2; ct++) {
        const int n0 = ct * 128 + wc * 64;
#pragma unroll
        for (int ks = 0; ks < 4; ks++) {
            h8 af[4], bf[4];
#pragma unroll
            for (int t = 0; t < 4; t++) {
                af[t] = *(const h8*)&As[(wr * 64 + t * 16 + lm) * LDA + ks * 32 + lq * 8];
                bf[t] = *(const h8*)&Wt[(size_t)(n0 + t * 16 + lm) * K + ks * 32 + lq * 8];
            }
#pragma unroll
            for (int i = 0; i < 4; i++)
#pragma unroll
                for (int j = 0; j < 4; j++)
                    acc[i][ct * 4 + j] =
                        __builtin_amdgcn_mfma_f32_16x16x32_f16(af[i], bf[j], acc[i][ct * 4 + j], 0, 0, 0);
        }
    }

    float bv[8];
#pragma unroll
    for (int jj = 0; jj < 8; jj++) bv[jj] = bias[(jj >> 2) * 128 + wc * 64 + (jj & 3) * 16 + lm];
    float ls[8] = {0, 0, 0, 0, 0, 0, 0, 0}, lsq[8] = {0, 0, 0, 0, 0, 0, 0, 0};
    _Float16* Cs = As;
    const int trow = tid >> 4;
    const int tcol = (tid & 15) * 8;
#pragma unroll
    for (int half = 0; half < 2; half++) {
        __syncthreads();
#pragma unroll
        for (int i = 0; i < 4; i++) {
            int row = wr * 64 + i * 16 + lq * 4;
#pragma unroll
            for (int j = 0; j < 4; j++) {
                int jj = half * 4 + j;
#pragma unroll
                for (int r = 0; r < 4; r++) {
                    float v = acc[i][jj][r] + bv[jj];
                    Cs[(row + r) * LDA + wc * 64 + j * 16 + lm] = (_Float16)v;
                    if (mB + row + r < M) { ls[jj] += v; lsq[jj] += v * v; }
                }
            }
        }
        __syncthreads();
#pragma unroll
        for (int p = 0; p < 8; p++) {
            int row = p * 16 + trow;
            int grow = mB + row;
            if (grow < M) {
                h8 v = *(const h8*)&Cs[row * LDA + tcol];
                *(h8*)&C[(size_t)grow * NCF + half * 128 + tcol] = v;
            }
        }
    }
    const int stripe = blockIdx.x & (NSTRIPE - 1);
#pragma unroll
    for (int jj = 0; jj < 8; jj++) {
        float s = ls[jj], q = lsq[jj];
        s += __shfl_xor(s, 16); s += __shfl_xor(s, 32);
        q += __shfl_xor(q, 16); q += __shfl_xor(q, 32);
        if (lq == 0) {
            int col = (jj >> 2) * 128 + wc * 64 + (jj & 3) * 16 + lm;
            atomicAdd(&csum[stripe * NCF + col], s);
            atomicAdd(&csq[stripe * NCF + col], q);
        }
    }
}

// ---- GEMM2: C[M x 128] = relu(bn(A))[M x 256] @ W + bias ----------------
// BN+ReLU on A fused into staging via precomputed bnsc/bnsh[256].
__global__ __launch_bounds__(256, 2) void gemmB_k(
        const _Float16* __restrict__ A, const _Float16* __restrict__ Wt,
        const float* __restrict__ bias, _Float16* __restrict__ C,
        float* __restrict__ csum, float* __restrict__ csq, int M,
        const float* __restrict__ bnsc, const float* __restrict__ bnsh) {
    constexpr int K = 256, NCF = 128, BK = 128;
    constexpr int LDA = BK + 8;
    __shared__ __align__(16) _Float16 As[128 * LDA];
    const int tid = threadIdx.x;
    const int lane = tid & 63;
    const int wave = tid >> 6;
    const int wr = wave & 1, wc = wave >> 1;
    const int lm = lane & 15, lq = lane >> 4;
    const int mB = blockIdx.x * 128;
    const int n0 = wc * 64;

    f4 acc[4][4];
#pragma unroll
    for (int i = 0; i < 4; i++)
#pragma unroll
        for (int j = 0; j < 4; j++) acc[i][j] = (f4){0.f, 0.f, 0.f, 0.f};

    const int sr = tid >> 4;
    const int sc = (tid & 15) * 8;

    for (int kc = 0; kc < K; kc += BK) {
        if (kc) __syncthreads();
        float bscv[8], bshv[8];
        {
            float4 s0 = *(const float4*)&bnsc[kc + sc];
            float4 s1 = *(const float4*)&bnsc[kc + sc + 4];
            float4 t0 = *(const float4*)&bnsh[kc + sc];
            float4 t1 = *(const float4*)&bnsh[kc + sc + 4];
            bscv[0] = s0.x; bscv[1] = s0.y; bscv[2] = s0.z; bscv[3] = s0.w;
            bscv[4] = s1.x; bscv[5] = s1.y; bscv[6] = s1.z; bscv[7] = s1.w;
            bshv[0] = t0.x; bshv[1] = t0.y; bshv[2] = t0.z; bshv[3] = t0.w;
            bshv[4] = t1.x; bshv[5] = t1.y; bshv[6] = t1.z; bshv[7] = t1.w;
        }
#pragma unroll
        for (int rr = 0; rr < 128; rr += 16) {
            int gr = mB + rr + sr; if (gr >= M) gr = M - 1;
            h8 h = *(const h8*)&A[(size_t)gr * K + kc + sc];
#pragma unroll
            for (int e = 0; e < 8; e++)
                h[e] = (_Float16)fmaxf((float)h[e] * bscv[e] + bshv[e], 0.f);
            *(h8*)&As[(rr + sr) * LDA + sc] = h;
        }
        __syncthreads();
#pragma unroll
        for (int ks = 0; ks < BK / 32; ks++) {
            h8 af[4], bf[4];
#pragma unroll
            for (int t = 0; t < 4; t++) {
                af[t] = *(const h8*)&As[(wr * 64 + t * 16 + lm) * LDA + ks * 32 + lq * 8];
                bf[t] = *(const h8*)&Wt[(size_t)(n0 + t * 16 + lm) * K + kc + ks * 32 + lq * 8];
            }
#pragma unroll
            for (int i = 0; i < 4; i++)
#pragma unroll
                for (int j = 0; j < 4; j++)
                    acc[i][j] = __builtin_amdgcn_mfma_f32_16x16x32_f16(af[i], bf[j], acc[i][j], 0, 0, 0);
        }
    }

    float bv[4];
#pragma unroll
    for (int j = 0; j < 4; j++) bv[j] = bias[n0 + j * 16 + lm];
    float ls[4] = {0, 0, 0, 0}, lsq[4] = {0, 0, 0, 0};
    __syncthreads();
    _Float16* Cs = As;
#pragma unroll
    for (int i = 0; i < 4; i++) {
        int row = wr * 64 + i * 16 + lq * 4;
        bool rv[4];
#pragma unroll
        for (int r = 0; r < 4; r++) rv[r] = (mB + row + r) < M;
#pragma unroll
        for (int j = 0; j < 4; j++) {
#pragma unroll
            for (int r = 0; r < 4; r++) {
                float v = acc[i][j][r] + bv[j];
                Cs[(row + r) * LDA + wc * 64 + j * 16 + lm] = (_Float16)v;
                if (rv[r]) { ls[j] += v; lsq[j] += v * v; }
            }
        }
    }
    const int stripe = blockIdx.x & (NSTRIPE - 1);
#pragma unroll
    for (int j = 0; j < 4; j++) {
        float s = ls[j], q = lsq[j];
        s += __shfl_xor(s, 16); s += __shfl_xor(s, 32);
        q += __shfl_xor(q, 16); q += __shfl_xor(q, 32);
        if (lq == 0) {
            atomicAdd(&csum[stripe * NCF + n0 + j * 16 + lm], s);
            atomicAdd(&csq[stripe * NCF + n0 + j * 16 + lm], q);
        }
    }
    __syncthreads();
    const int trow = tid >> 4;
    const int tcol = (tid & 15) * 8;
#pragma unroll
    for (int p = 0; p < 8; p++) {
        int row = p * 16 + trow;
        int grow = mB + row;
        if (grow < M) {
            h8 v = *(const h8*)&Cs[row * LDA + tcol];
            *(h8*)&C[(size_t)grow * NCF + tcol] = v;
        }
    }
}

// ---- BN apply + relu (+optional vn-add after relu), f16 io, f32 math ----
__global__ void bnrelu_k(const _Float16* __restrict__ in, _Float16* __restrict__ out,
                         const float* __restrict__ scale, const float* __restrict__ shift,
                         const _Float16* __restrict__ vfeat, const int* __restrict__ batch,
                         int M) {
    constexpr int PER = 16;
    int tid = blockIdx.x * blockDim.x + threadIdx.x;
    int c8 = tid % PER;
    int c0 = c8 * 8;
    float sc[8], sh[8];
    float4 s0 = *(const float4*)&scale[c0];
    float4 s1 = *(const float4*)&scale[c0 + 4];
    float4 t0 = *(const float4*)&shift[c0];
    float4 t1 = *(const float4*)&shift[c0 + 4];
    sc[0] = s0.x; sc[1] = s0.y; sc[2] = s0.z; sc[3] = s0.w;
    sc[4] = s1.x; sc[5] = s1.y; sc[6] = s1.z; sc[7] = s1.w;
    sh[0] = t0.x; sh[1] = t0.y; sh[2] = t0.z; sh[3] = t0.w;
    sh[4] = t1.x; sh[5] = t1.y; sh[6] = t1.z; sh[7] = t1.w;
    int total = M * PER;
    int stride = gridDim.x * blockDim.x;
    for (int i = tid; i < total; i += stride) {
        int row = i / PER;
        h8 u = ((const h8*)in)[i];
        h8 w;
        bool vn = (vfeat != nullptr);
        if (vn) w = ((const h8*)vfeat)[batch[row] * PER + c8];
        h8 o;
#pragma unroll
        for (int e = 0; e < 8; e++) {
            float vv = fmaxf((float)u[e] * sc[e] + sh[e], 0.f);
            if (vn) vv += (float)w[e];
            o[e] = (_Float16)vv;
        }
        ((h8*)out)[i] = o;
    }
}

// ---- BN apply + segment-sum pool over sorted batch (NC=128) -------------
__global__ __launch_bounds__(256) void bnpool_k(
        const _Float16* __restrict__ in, _Float16* __restrict__ out,
        const float* __restrict__ scale, const float* __restrict__ shift,
        const int* __restrict__ batch, float* __restrict__ pooled,
        int M, int relu) {
    int t = threadIdx.x;
    int c0 = (t & 63) * 2;
    int r0 = blockIdx.x * 128 + (t >> 6) * 32;
    float sc0 = scale[c0], h0 = shift[c0];
    float sc1 = scale[c0 + 1], h1 = shift[c0 + 1];
    int rend = r0 + 32; if (rend > M) rend = M;
    float a0 = 0.f, a1 = 0.f; int cur = -1;
    int r = r0;
    for (; r + 1 < rend; r += 2) {
        h2 ua = ((const h2*)in)[(size_t)r * 64 + (c0 >> 1)];
        h2 ub = ((const h2*)in)[(size_t)(r + 1) * 64 + (c0 >> 1)];
        int bga = batch[r], bgb = batch[r + 1];
        float va0 = (float)ua.x * sc0 + h0, va1 = (float)ua.y * sc1 + h1;
        float vb0 = (float)ub.x * sc0 + h0, vb1 = (float)ub.y * sc1 + h1;
        if (relu) {
            va0 = fmaxf(va0, 0.f); va1 = fmaxf(va1, 0.f);
            vb0 = fmaxf(vb0, 0.f); vb1 = fmaxf(vb1, 0.f);
        }
        if (out) {
            h2 oa; oa.x = (_Float16)va0; oa.y = (_Float16)va1;
            h2 ob; ob.x = (_Float16)vb0; ob.y = (_Float16)vb1;
            ((h2*)out)[(size_t)r * 64 + (c0 >> 1)] = oa;
            ((h2*)out)[(size_t)(r + 1) * 64 + (c0 >> 1)] = ob;
        }
        if (bga != cur) {
            if (cur >= 0) {
                atomicAdd(&pooled[(size_t)cur * DH + c0], a0);
                atomicAdd(&pooled[(size_t)cur * DH + c0 + 1], a1);
            }
            cur = bga; a0 = 0.f; a1 = 0.f;
        }
        a0 += va0; a1 += va1;
        if (bgb != cur) {
            atomicAdd(&pooled[(size_t)cur * DH + c0], a0);
            atomicAdd(&pooled[(size_t)cur * DH + c0 + 1], a1);
            cur = bgb; a0 = 0.f; a1 = 0.f;
        }
        a0 += vb0; a1 += vb1;
    }
    for (; r < rend; r++) {
        h2 u = ((const h2*)in)[(size_t)r * 64 + (c0 >> 1)];
        float v0 = (float)u.x * sc0 + h0;
        float v1 = (float)u.y * sc1 + h1;
        if (relu) { v0 = fmaxf(v0, 0.f); v1 = fmaxf(v1, 0.f); }
        if (out) { h2 o; o.x = (_Float16)v0; o.y = (_Float16)v1; ((h2*)out)[(size_t)r * 64 + (c0 >> 1)] = o; }
        int bg = batch[r];
        if (bg != cur) {
            if (cur >= 0) {
                atomicAdd(&pooled[(size_t)cur * DH + c0], a0);
                atomicAdd(&pooled[(size_t)cur * DH + c0 + 1], a1);
            }
            cur = bg; a0 = 0.f; a1 = 0.f;
        }
        a0 += v0; a1 += v1;
    }
    if (cur >= 0) {
        atomicAdd(&pooled[(size_t)cur * DH + c0], a0);
        atomicAdd(&pooled[(size_t)cur * DH + c0 + 1], a1);
    }
}

// ------------------------------------------------------------------------
extern "C" void kernel_launch(void* const* d_in, const int* in_sizes, int n_in,
                              void* d_out, int out_size, void* d_ws, size_t ws_size,
                              hipStream_t stream) {
    const float* x      = (const float*)d_in[0];
    const int*   ei     = (const int*)d_in[1];
    const int*   batch  = (const int*)d_in[2];
    const float* vn_emb = (const float*)d_in[3];
    const float* c1_W1  = (const float*)d_in[4];
    const float* c1_b1  = (const float*)d_in[5];
    const float* c1_bng = (const float*)d_in[6];
    const float* c1_bnb = (const float*)d_in[7];
    const float* c1_W2  = (const float*)d_in[8];
    const float* c1_b2  = (const float*)d_in[9];
    const float* bn1_g  = (const float*)d_in[10];
    const float* bn1_b  = (const float*)d_in[11];
    const float* cW1    = (const float*)d_in[12];
    const float* cb1    = (const float*)d_in[13];
    const float* cbng   = (const float*)d_in[14];
    const float* cbnb   = (const float*)d_in[15];
    const float* cW2    = (const float*)d_in[16];
    const float* cb2    = (const float*)d_in[17];
    const float* bns_g  = (const float*)d_in[18];
    const float* bns_b  = (const float*)d_in[19];
    const float* vW1    = (const float*)d_in[20];
    const float* vb1    = (const float*)d_in[21];
    const float* vbn1_g = (const float*)d_in[22];
    const float* vbn1_b = (const float*)d_in[23];
    const float* vW2    = (const float*)d_in[24];
    const float* vb2    = (const float*)d_in[25];
    const float* vbn2_g = (const float*)d_in[26];
    const float* vbn2_b = (const float*)d_in[27];
    float* outp = (float*)d_out;
    (void)in_sizes; (void)n_in; (void)out_size; (void)ws_size;

    char* w = (char*)d_ws;
    size_t off = 0;
    auto carve = [&](size_t bytes) -> void* {
        void* p = w + off; off = align256(off + bytes); return p;
    };
    // zero-init region
    int*   cursor  = (int*)carve((size_t)NN * 4);
    float* pooled  = (float*)carve((size_t)NG * DH * 4);
    float* pooled2 = (float*)carve((size_t)NG * DH * 4);
    float *sA[3], *qA[3], *sB[3], *qB[3], *sV1, *qV1, *sV2, *qV2;
    for (int i = 0; i < 3; i++) {
        sA[i] = (float*)carve((size_t)NSTRIPE * 256 * 4);
        qA[i] = (float*)carve((size_t)NSTRIPE * 256 * 4);
    }
    for (int i = 0; i < 3; i++) {
        sB[i] = (float*)carve((size_t)NSTRIPE * 128 * 4);
        qB[i] = (float*)carve((size_t)NSTRIPE * 128 * 4);
    }
    sV1 = (float*)carve((size_t)NSTRIPE * 256 * 4);
    qV1 = (float*)carve((size_t)NSTRIPE * 256 * 4);
    sV2 = (float*)carve((size_t)NSTRIPE * 128 * 4);
    qV2 = (float*)carve((size_t)NSTRIPE * 128 * 4);
    size_t zbytes = off;
    // non-zeroed region
    float *scA[3], *shA[3], *scB[3], *shB[3];
    for (int i = 0; i < 3; i++) { scA[i] = (float*)carve(256 * 4); shA[i] = (float*)carve(256 * 4); }
    for (int i = 0; i < 3; i++) { scB[i] = (float*)carve(128 * 4); shB[i] = (float*)carve(128 * 4); }
    float* scV1 = (float*)carve(256 * 4); float* shV1 = (float*)carve(256 * 4);
    float* scV2 = (float*)carve(128 * 4); float* shV2 = (float*)carve(128 * 4);
    int*   gcnt    = (int*)carve((size_t)NG * 4);
    int*   rowptr  = (int*)carve((size_t)(NN + 1) * 4);
    int*   slot    = (int*)carve((size_t)NE * 4);
    int*   esrc    = (int*)carve((size_t)NE * 4);
    int*   part    = (int*)carve((size_t)SCB * 4);
    _Float16* vfeat = (_Float16*)carve((size_t)NG * DH * 2);
    _Float16* zin   = (_Float16*)carve((size_t)NG * DH * 2);
    _Float16* zb    = (_Float16*)carve((size_t)NG * DH2 * 2);
    _Float16* vraw  = (_Float16*)carve((size_t)NG * DH * 2);
    _Float16* xh    = (_Float16*)carve((size_t)NN * DH * 2);
    _Float16* hb    = (_Float16*)carve((size_t)NN * DH * 2);
    _Float16* b1    = (_Float16*)carve((size_t)NN * DH2 * 2);
    _Float16* abuf  = (_Float16*)carve((size_t)NN * DH * 2);
    _Float16* Wt[8];
    for (int i = 0; i < 8; i++) Wt[i] = (_Float16*)carve((size_t)DH * DH2 * 2);

    WPack wp;
    wp.w[0] = c1_W1;            wp.K[0] = 128; wp.N[0] = 256;
    wp.w[1] = c1_W2;            wp.K[1] = 256; wp.N[1] = 128;
    wp.w[2] = cW1;              wp.K[2] = 128; wp.N[2] = 256;
    wp.w[3] = cW2;              wp.K[3] = 256; wp.N[3] = 128;
    wp.w[4] = cW1 + 128 * 256;  wp.K[4] = 128; wp.N[4] = 256;
    wp.w[5] = cW2 + 256 * 128;  wp.K[5] = 256; wp.N[5] = 128;
    wp.w[6] = vW1;              wp.K[6] = 128; wp.N[6] = 256;
    wp.w[7] = vW2;              wp.K[7] = 256; wp.N[7] = 128;
    for (int i = 0; i < 8; i++) wp.wt[i] = Wt[i];

    const int GB = (NN + 127) / 128;  // 782

    hipMemsetAsync(d_ws, 0, zbytes, stream);
    countslot_k<<<782, 256, 0, stream>>>(ei, cursor, slot);
    scan1_k<<<SCB, 256, 0, stream>>>(cursor, part);
    scan2_k<<<1, 64, 0, stream>>>(part, rowptr);
    scan3_k<<<SCB, 256, 0, stream>>>(cursor, part, rowptr);
    place_k<<<782, 256, 0, stream>>>(ei, rowptr, slot, esrc);
    gbound_k<<<2, 256, 0, stream>>>(batch, gcnt);
    wtrans_k<<<dim3(8, 8, 8), 256, 0, stream>>>(wp);
    vinit_k<<<(NG * DH + 255) / 256, 256, 0, stream>>>(vn_emb, vfeat);
    castx_k<<<(NN * 16 + 255) / 256, 256, 0, stream>>>(x, xh);

    // ---- layer 1 ----
    agg_k<<<NN / 4, 256, 0, stream>>>(xh, rowptr, esrc, hb);
    gemmA_k<<<GB, 256, 0, stream>>>(hb, Wt[0], c1_b1, b1, sA[0], qA[0], NN);
    bnfin_k<<<1, 256, 0, stream>>>(sA[0], qA[0], c1_bng, c1_bnb, scA[0], shA[0], 256, NN);
    gemmB_k<<<GB, 256, 0, stream>>>(b1, Wt[1], c1_b2, abuf, sB[0], qB[0], NN, scA[0], shA[0]);
    bnfin_k<<<1, 256, 0, stream>>>(sB[0], qB[0], bn1_g, bn1_b, scB[0], shB[0], 128, NN);
    bnrelu_k<<<2048, 256, 0, stream>>>(abuf, abuf, scB[0], shB[0], vfeat, batch, NN);

    // ---- layer 2 ----
    agg_k<<<NN / 4, 256, 0, stream>>>(abuf, rowptr, esrc, hb);
    gemmA_k<<<GB, 256, 0, stream>>>(hb, Wt[2], cb1, b1, sA[1], qA[1], NN);
    bnfin_k<<<1, 256, 0, stream>>>(sA[1], qA[1], cbng, cbnb, scA[1], shA[1], 256, NN);
    gemmB_k<<<GB, 256, 0, stream>>>(b1, Wt[3], cb2, abuf, sB[1], qB[1], NN, scA[1], shA[1]);
    bnfin_k<<<1, 256, 0, stream>>>(sB[1], qB[1], bns_g, bns_b, scB[1], shB[1], 128, NN);
    bnpool_k<<<GB, 256, 0, stream>>>(abuf, abuf, scB[1], shB[1], batch, pooled, NN, 1);

    // ---- virtual-node MLP (M = 512) ----
    zin_k<<<(NG * DH + 255) / 256, 256, 0, stream>>>(pooled, vfeat, zin);
    gemmA_k<<<4, 256, 0, stream>>>(zin, Wt[6], vb1, zb, sV1, qV1, NG);
    bnfin_k<<<1, 256, 0, stream>>>(sV1, qV1, vbn1_g, vbn1_b, scV1, shV1, 256, NG);
    gemmB_k<<<4, 256, 0, stream>>>(zb, Wt[7], vb2, vraw, sV2, qV2, NG, scV1, shV1);
    bnfin_k<<<1, 256, 0, stream>>>(sV2, qV2, vbn2_g, vbn2_b, scV2, shV2, 128, NG);
    bnrelu_k<<<32, 256, 0, stream>>>(vraw, vfeat, scV2, shV2, nullptr, nullptr, NG);

    // ---- layer 3 ----
    addvn_k<<<(NN * 16 + 255) / 256, 256, 0, stream>>>(abuf, vfeat, batch);
    agg_k<<<NN / 4, 256, 0, stream>>>(abuf, rowptr, esrc, hb);
    gemmA_k<<<GB, 256, 0, stream>>>(hb, Wt[4], cb1 + 256, b1, sA[2], qA[2], NN);
    bnfin_k<<<1, 256, 0, stream>>>(sA[2], qA[2], cbng + 256, cbnb + 256, scA[2], shA[2], 256, NN);
    gemmB_k<<<GB, 256, 0, stream>>>(b1, Wt[5], cb2 + 128, abuf, sB[2], qB[2], NN, scA[2], shA[2]);
    bnfin_k<<<1, 256, 0, stream>>>(sB[2], qB[2], bns_g + 128, bns_b + 128, scB[2], shB[2], 128, NN);
    bnpool_k<<<GB, 256, 0, stream>>>(abuf, nullptr, scB[2], shB[2], batch, pooled2, NN, 0);

    finalout_k<<<(NG * DH + 255) / 256, 256, 0, stream>>>(pooled2, gcnt, outp);
}